// Round 11
// baseline (764.017 us; speedup 1.0000x reference)
//
#include <hip/hip_runtime.h>
#include <hip/hip_bf16.h>
#include <math.h>

#define TILES 4
#define MBLK 64

typedef __attribute__((ext_vector_type(8))) short bf8;
typedef __attribute__((ext_vector_type(4))) float f32x4;

#define MFMA(a, b, c) __builtin_amdgcn_mfma_f32_16x16x32_bf16(a, b, c, 0, 0, 0)

__device__ __forceinline__ float fast_rcp(float x) { return __builtin_amdgcn_rcpf(x); }
#if __has_builtin(__builtin_amdgcn_exp2f)
__device__ __forceinline__ float exp2b(float x) { return __builtin_amdgcn_exp2f(x); }
#else
__device__ __forceinline__ float exp2b(float x) { return exp2f(x); }
#endif
// log2e-prefolded sigmoid/tanh
__device__ __forceinline__ float sigm2(float xp) { return fast_rcp(1.0f + exp2b(-xp)); }
__device__ __forceinline__ float tanh2s(float up) {
    return fmaf(2.0f, fast_rcp(1.0f + exp2b(-up)), -1.0f);
}
// unscaled versions (s2s LSTM)
__device__ __forceinline__ float sigm(float x) { return fast_rcp(1.0f + __expf(-x)); }
__device__ __forceinline__ float tanh2(float x) { return fmaf(2.0f, fast_rcp(1.0f + __expf(-2.0f * x)), -1.0f); }

__device__ __forceinline__ unsigned short f2bf(float v) {
    union { __hip_bfloat16 b; unsigned short u; } cv;
    cv.b = __float2bfloat16(v);
    return cv.u;
}
__device__ __forceinline__ float bf2f(unsigned short u) {
    union { unsigned short u; __hip_bfloat16 b; } cv;
    cv.u = u;
    return __bfloat162float(cv.b);
}
// truncation split: hi = upper 16 bits (RTZ), lo = RNE(v - hi). err ~2^-17 rel.
__device__ __forceinline__ void split_tr(float v, unsigned short& hi, unsigned short& lo) {
    unsigned int uv = __builtin_bit_cast(unsigned int, v);
    hi = (unsigned short)(uv >> 16);
    float rem = v - __builtin_bit_cast(float, uv & 0xffff0000u);
    lo = f2bf(rem);
}
__device__ __forceinline__ f32x4 ntload4(const float* p) {
    return __builtin_nontemporal_load((const f32x4*)p);
}

// ---------------------------------------------------------------------------
// prep: node-weight split-bf16 frags (MFMA A operand; lane&15 = weight row j),
// GRU gate rows pre-scaled by log2e (r/z) and 2*log2e (n). LSTM transposes,
// l2 transpose, segment starts. (unchanged)
// ---------------------------------------------------------------------------
__global__ void prep_kernel(const float* __restrict__ l0w, const float* __restrict__ l1w,
                            const float* __restrict__ gwih, const float* __restrict__ gwhh,
                            const float* __restrict__ lwih, const float* __restrict__ lwhh,
                            const float* __restrict__ l2w,
                            const int* __restrict__ batch,
                            unsigned short* __restrict__ whi, unsigned short* __restrict__ wlo,
                            float* __restrict__ liT, float* __restrict__ lhT,
                            float* __restrict__ l2T,
                            int* __restrict__ startp,
                            int n_nodes, int n_graphs)
{
    int tid = blockIdx.x * 256 + threadIdx.x;
    if (tid < 32768) {
        int e = tid & 7, lane = (tid >> 3) & 63, ks = (tid >> 9) & 1, jt = tid >> 10;
        const float* W; int jl;
        if (jt < 4)       { W = l0w;  jl = jt; }
        else if (jt < 8)  { W = l1w;  jl = jt - 4; }
        else if (jt < 20) { W = gwih; jl = jt - 8; }
        else              { W = gwhh; jl = jt - 20; }
        int j = jl * 16 + (lane & 15);
        int k = ks * 32 + (lane >> 4) * 8 + e;
        float v = W[j * 64 + k];
        if (jt >= 8) v *= (j < 128) ? 1.44269504f : 2.88539008f;  // log2e / 2*log2e
        unsigned short hi = f2bf(v);
        whi[tid] = hi;
        wlo[tid] = f2bf(v - bf2f(hi));
    }
    if (tid < 32768) liT[tid] = lwih[(tid & 255) * 128 + (tid >> 8)];  // liT[k*256+j]
    if (tid < 16384) lhT[tid] = lwhh[(tid & 255) * 64 + (tid >> 8)];   // lhT[k*256+j]
    if (tid < 8192)  l2T[tid] = l2w[(tid & 63) * 128 + (tid >> 6)];    // l2T[k*64+d]
    if (tid <= n_graphs) {
        int lo = 0, hi = n_nodes;
        while (lo < hi) {
            int mid = (lo + hi) >> 1;
            if (batch[mid] < tid) lo = mid + 1; else hi = mid;
        }
        startp[tid] = lo;
    }
}

// ---------------------------------------------------------------------------
// node pipeline, flipped operands (A=weights). Round-11 changes:
//  - H double-buffered: gates read H[cur], write h to H[cur^1] inline ->
//    3 barriers/iter -> 2, no separate h-write phase.
//  - s_setprio(1) around MFMA clusters (T5: phase-diverse co-resident blocks).
// Occupancy is register-capped at 2 waves/SIMD (32 weight frags = 128 regs +
// acc); LDS 48KB is free at 2 blocks/CU.
// ---------------------------------------------------------------------------
__launch_bounds__(256, 2)
__global__ void node_kernel(const float* __restrict__ x,
                            const unsigned short* __restrict__ whi,
                            const unsigned short* __restrict__ wlo,
                            const float* __restrict__ l0b, const float* __restrict__ l1b,
                            const float* __restrict__ gbih, const float* __restrict__ gbhh,
                            float* __restrict__ outv, int n_nodes)
{
    __shared__ unsigned short MHI[TILES * 1024], MLO[TILES * 1024];
    __shared__ unsigned short HHI[2][TILES * 1024], HLO[2][TILES * 1024];
    const int tid = threadIdx.x;
    const int w = tid >> 6, lane = tid & 63, c = lane & 15, g = lane >> 4;
    const long node0 = (long)blockIdx.x * MBLK;
    const int j0 = w * 16 + g * 4;     // this thread's 4 channels (C rows)

    const float LOG2E = 1.44269504f;
    float bR[4], bZ[4], bNI[4], bNH[4], bL0[4], bL1[4];
#pragma unroll
    for (int p = 0; p < 4; ++p) {
        bR[p]  = (gbih[j0 + p] + gbhh[j0 + p]) * LOG2E;
        bZ[p]  = (gbih[64 + j0 + p] + gbhh[64 + j0 + p]) * LOG2E;
        bNI[p] = gbih[128 + j0 + p] * (2.0f * LOG2E);
        bNH[p] = gbhh[128 + j0 + p] * (2.0f * LOG2E);
        bL0[p] = l0b[j0 + p];
        bL1[p] = l1b[j0 + p];
    }

    // LDS write addr (u16): granule(node=c, kg=w*2+(g>>1)), elems (g&1)*4+p
    const int waddr = ((w >> 1) * 512) + (((w & 1) * 2 + (g >> 1)) * 128)
                    + (c * 8) + ((g & 1) * 4);

    const bf8* WH = (const bf8*)whi;
    const bf8* WL = (const bf8*)wlo;
#define LF(name, jt) \
    bf8 name##h0 = WH[((jt) * 2 + 0) * 64 + lane], name##h1 = WH[((jt) * 2 + 1) * 64 + lane], \
        name##l0 = WL[((jt) * 2 + 0) * 64 + lane], name##l1 = WL[((jt) * 2 + 1) * 64 + lane];
    LF(w0, w)
    LF(w1, 4 + w)
    LF(gir, 8 + w)  LF(giz, 12 + w)  LF(gin, 16 + w)
    LF(ghr, 20 + w) LF(ghz, 24 + w) LF(ghn, 28 + w)
#undef LF

    float hc[TILES][4];   // hc[t][p] = h[channel j0+p][node t*16+c]

    // ---- lin0: h = relu(W0 x + b0) -> H[0] ----
#pragma unroll
    for (int t = 0; t < TILES; ++t) {
        long nd = node0 + t * 16 + c;
        if (nd >= n_nodes) nd = n_nodes - 1;
        const float* xp = x + nd * 64 + g * 8;
        float va[8], vb[8];
        {
            float4 u0 = *(const float4*)xp;
            float4 u1 = *(const float4*)(xp + 4);
            float4 u2 = *(const float4*)(xp + 32);
            float4 u3 = *(const float4*)(xp + 36);
            va[0] = u0.x; va[1] = u0.y; va[2] = u0.z; va[3] = u0.w;
            va[4] = u1.x; va[5] = u1.y; va[6] = u1.z; va[7] = u1.w;
            vb[0] = u2.x; vb[1] = u2.y; vb[2] = u2.z; vb[3] = u2.w;
            vb[4] = u3.x; vb[5] = u3.y; vb[6] = u3.z; vb[7] = u3.w;
        }
        bf8 xh0, xl0, xh1, xl1;
#pragma unroll
        for (int e = 0; e < 8; ++e) {
            unsigned short h0, l0, h1, l1;
            split_tr(va[e], h0, l0);
            split_tr(vb[e], h1, l1);
            xh0[e] = (short)h0; xl0[e] = (short)l0;
            xh1[e] = (short)h1; xl1[e] = (short)l1;
        }
        f32x4 acc = {bL0[0], bL0[1], bL0[2], bL0[3]};
        __builtin_amdgcn_s_setprio(1);
        acc = MFMA(w0h0, xh0, acc); acc = MFMA(w0h0, xl0, acc); acc = MFMA(w0l0, xh0, acc);
        acc = MFMA(w0h1, xh1, acc); acc = MFMA(w0h1, xl1, acc); acc = MFMA(w0l1, xh1, acc);
        __builtin_amdgcn_s_setprio(0);
        unsigned short sh[4], sl[4];
#pragma unroll
        for (int p = 0; p < 4; ++p) {
            float hv = fmaxf(acc[p], 0.0f);
            hc[t][p] = hv;
            split_tr(hv, sh[p], sl[p]);
        }
        *(short4*)&HHI[0][t * 1024 + waddr] = make_short4((short)sh[0], (short)sh[1], (short)sh[2], (short)sh[3]);
        *(short4*)&HLO[0][t * 1024 + waddr] = make_short4((short)sl[0], (short)sl[1], (short)sl[2], (short)sl[3]);
    }
    __syncthreads();

#pragma unroll
    for (int iter = 0; iter < 3; ++iter) {
        const int cur = iter & 1;
        const int nxt = cur ^ 1;
        // ---- lin1: m = relu(W1 h + b1), reads H[cur] -> M ----
#pragma unroll
        for (int t = 0; t < TILES; ++t) {
            const bf8* hh = (const bf8*)&HHI[cur][t * 1024];
            const bf8* hl = (const bf8*)&HLO[cur][t * 1024];
            bf8 ah0 = hh[lane], ah1 = hh[64 + lane];
            bf8 al0 = hl[lane], al1 = hl[64 + lane];
            f32x4 acc = {bL1[0], bL1[1], bL1[2], bL1[3]};
            __builtin_amdgcn_s_setprio(1);
            acc = MFMA(w1h0, ah0, acc); acc = MFMA(w1h0, al0, acc); acc = MFMA(w1l0, ah0, acc);
            acc = MFMA(w1h1, ah1, acc); acc = MFMA(w1h1, al1, acc); acc = MFMA(w1l1, ah1, acc);
            __builtin_amdgcn_s_setprio(0);
            unsigned short sh[4], sl[4];
#pragma unroll
            for (int p = 0; p < 4; ++p) {
                float mv = fmaxf(acc[p], 0.0f);
                split_tr(mv, sh[p], sl[p]);
            }
            *(short4*)&MHI[t * 1024 + waddr] = make_short4((short)sh[0], (short)sh[1], (short)sh[2], (short)sh[3]);
            *(short4*)&MLO[t * 1024 + waddr] = make_short4((short)sl[0], (short)sl[1], (short)sl[2], (short)sl[3]);
        }
        __syncthreads();

        // ---- GRU gates: read M + H[cur], write h -> H[nxt] inline ----
#pragma unroll
        for (int t = 0; t < TILES; ++t) {
            const bf8* mh = (const bf8*)&MHI[t * 1024];
            const bf8* ml = (const bf8*)&MLO[t * 1024];
            const bf8* hh = (const bf8*)&HHI[cur][t * 1024];
            const bf8* hl = (const bf8*)&HLO[cur][t * 1024];
            bf8 amh0 = mh[lane], amh1 = mh[64 + lane];
            bf8 aml0 = ml[lane], aml1 = ml[64 + lane];
            bf8 ahh0 = hh[lane], ahh1 = hh[64 + lane];
            bf8 ahl0 = hl[lane], ahl1 = hl[64 + lane];

            f32x4 aR  = {bR[0], bR[1], bR[2], bR[3]};
            f32x4 aZ  = {bZ[0], bZ[1], bZ[2], bZ[3]};
            f32x4 aNI = {bNI[0], bNI[1], bNI[2], bNI[3]};
            f32x4 aNH = {bNH[0], bNH[1], bNH[2], bNH[3]};

            __builtin_amdgcn_s_setprio(1);
            aR = MFMA(girh0, amh0, aR); aR = MFMA(girh0, aml0, aR); aR = MFMA(girl0, amh0, aR);
            aR = MFMA(girh1, amh1, aR); aR = MFMA(girh1, aml1, aR); aR = MFMA(girl1, amh1, aR);
            aR = MFMA(ghrh0, ahh0, aR); aR = MFMA(ghrh0, ahl0, aR); aR = MFMA(ghrl0, ahh0, aR);
            aR = MFMA(ghrh1, ahh1, aR); aR = MFMA(ghrh1, ahl1, aR); aR = MFMA(ghrl1, ahh1, aR);

            aZ = MFMA(gizh0, amh0, aZ); aZ = MFMA(gizh0, aml0, aZ); aZ = MFMA(gizl0, amh0, aZ);
            aZ = MFMA(gizh1, amh1, aZ); aZ = MFMA(gizh1, aml1, aZ); aZ = MFMA(gizl1, amh1, aZ);
            aZ = MFMA(ghzh0, ahh0, aZ); aZ = MFMA(ghzh0, ahl0, aZ); aZ = MFMA(ghzl0, ahh0, aZ);
            aZ = MFMA(ghzh1, ahh1, aZ); aZ = MFMA(ghzh1, ahl1, aZ); aZ = MFMA(ghzl1, ahh1, aZ);

            aNI = MFMA(ginh0, amh0, aNI); aNI = MFMA(ginh0, aml0, aNI); aNI = MFMA(ginl0, amh0, aNI);
            aNI = MFMA(ginh1, amh1, aNI); aNI = MFMA(ginh1, aml1, aNI); aNI = MFMA(ginl1, amh1, aNI);

            aNH = MFMA(ghnh0, ahh0, aNH); aNH = MFMA(ghnh0, ahl0, aNH); aNH = MFMA(ghnl0, ahh0, aNH);
            aNH = MFMA(ghnh1, ahh1, aNH); aNH = MFMA(ghnh1, ahl1, aNH); aNH = MFMA(ghnl1, ahh1, aNH);
            __builtin_amdgcn_s_setprio(0);

            unsigned short sh[4], sl[4];
#pragma unroll
            for (int p = 0; p < 4; ++p) {
                float rg = sigm2(aR[p]);
                float zg = sigm2(aZ[p]);
                float ng = tanh2s(fmaf(rg, aNH[p], aNI[p]));
                float hv = fmaf(zg, hc[t][p] - ng, ng);
                hc[t][p] = hv;
                split_tr(hv, sh[p], sl[p]);
            }
            if (iter < 2) {
                *(short4*)&HHI[nxt][t * 1024 + waddr] = make_short4((short)sh[0], (short)sh[1], (short)sh[2], (short)sh[3]);
                *(short4*)&HLO[nxt][t * 1024 + waddr] = make_short4((short)sl[0], (short)sl[1], (short)sl[2], (short)sl[3]);
            }
        }
        if (iter < 2) __syncthreads();
    }

    // ---- store out: thread owns channels j0..j0+3 of node t*16+c ----
#pragma unroll
    for (int t = 0; t < TILES; ++t) {
        long nd = node0 + t * 16 + c;
        if (nd < n_nodes) {
            float4 o;
            o.x = hc[t][0]; o.y = hc[t][1]; o.z = hc[t][2]; o.w = hc[t][3];
            *(float4*)(outv + nd * 64 + j0) = o;
        }
    }
}

// ---------------------------------------------------------------------------
// FUSED Set2Set (3 steps) + head: block = 4 graphs. (unchanged)
// ---------------------------------------------------------------------------
__global__ void s2s_kernel(const float* __restrict__ outv,
                           const int* __restrict__ startp,
                           const float* __restrict__ liT, const float* __restrict__ lhT,
                           const float* __restrict__ lbih, const float* __restrict__ lbhh,
                           const float* __restrict__ l2T, const float* __restrict__ l2b,
                           const float* __restrict__ l3w, const float* __restrict__ l3b,
                           float* __restrict__ yout, int n_graphs)
{
    __shared__ float uS[4][192];   // per graph: [0:64) q, [64:128) r, [128:192) hl
    __shared__ float clS[4][64];
    __shared__ float mG[16], sG[16];
    __shared__ float rG[16][64];

    const int t = threadIdx.x;
    const int w = t >> 6, lane = t & 63;
    const int gbase = blockIdx.x * 4;
    const int grp = t >> 4, l = t & 15;

    uS[w][lane] = 0.0f; uS[w][64 + lane] = 0.0f; uS[w][128 + lane] = 0.0f;
    clS[w][lane] = 0.0f;
    __syncthreads();

    for (int step = 0; step < 3; ++step) {
        // ---- LSTM: wave w -> graph gbase+w, lane = channel d ----
        {
            const int d = lane;
            float aI = lbih[d]       + lbhh[d];
            float aF = lbih[64 + d]  + lbhh[64 + d];
            float aG = lbih[128 + d] + lbhh[128 + d];
            float aO = lbih[192 + d] + lbhh[192 + d];
            for (int k = 0; k < 128; ++k) {
                float uv = uS[w][k];
                const float* wr = liT + k * 256;
                aI = fmaf(wr[d], uv, aI);
                aF = fmaf(wr[64 + d], uv, aF);
                aG = fmaf(wr[128 + d], uv, aG);
                aO = fmaf(wr[192 + d], uv, aO);
            }
            for (int k = 0; k < 64; ++k) {
                float hv = uS[w][128 + k];
                const float* wr = lhT + k * 256;
                aI = fmaf(wr[d], hv, aI);
                aF = fmaf(wr[64 + d], hv, aF);
                aG = fmaf(wr[128 + d], hv, aG);
                aO = fmaf(wr[192 + d], hv, aO);
            }
            float c = sigm(aF) * clS[w][d] + sigm(aI) * tanh2(aG);
            clS[w][d] = c;
            float h = sigm(aO) * tanh2(c);
            uS[w][d] = h;        // q
            uS[w][128 + d] = h;  // hl
        }
        __syncthreads();

        // ---- attention: 4 graphs serially, all 256 threads each ----
        for (int idx = 0; idx < 4; ++idx) {
            const int g = gbase + idx;
            int s0 = 0, cnt = 0;
            if (g < n_graphs) { s0 = startp[g]; cnt = startp[g + 1] - s0; }

            const float q0 = uS[idx][l * 4 + 0], q1 = uS[idx][l * 4 + 1];
            const float q2 = uS[idx][l * 4 + 2], q3 = uS[idx][l * 4 + 3];

            float m = -INFINITY, s = 0.0f;
            float r0 = 0.0f, r1 = 0.0f, r2 = 0.0f, r3 = 0.0f;

            int n = grp;
            for (; n + 16 < cnt; n += 32) {
                f32x4 va = ntload4(outv + (size_t)(s0 + n) * 64 + l * 4);
                f32x4 vb = ntload4(outv + (size_t)(s0 + n + 16) * 64 + l * 4);
                float ea = fmaf(va.x, q0, fmaf(va.y, q1, fmaf(va.z, q2, va.w * q3)));
                float eb = fmaf(vb.x, q0, fmaf(vb.y, q1, fmaf(vb.z, q2, vb.w * q3)));
#pragma unroll
                for (int o = 1; o < 16; o <<= 1) {
                    ea += __shfl_xor(ea, o);
                    eb += __shfl_xor(eb, o);
                }
                float mn = fmaxf(m, fmaxf(ea, eb));
                float sc = __expf(m - mn);
                float wa = __expf(ea - mn);
                float wb = __expf(eb - mn);
                s = s * sc + wa + wb;
                r0 = fmaf(r0, sc, fmaf(wa, va.x, wb * vb.x));
                r1 = fmaf(r1, sc, fmaf(wa, va.y, wb * vb.y));
                r2 = fmaf(r2, sc, fmaf(wa, va.z, wb * vb.z));
                r3 = fmaf(r3, sc, fmaf(wa, va.w, wb * vb.w));
                m = mn;
            }
            if (n < cnt) {
                f32x4 va = ntload4(outv + (size_t)(s0 + n) * 64 + l * 4);
                float ea = fmaf(va.x, q0, fmaf(va.y, q1, fmaf(va.z, q2, va.w * q3)));
#pragma unroll
                for (int o = 1; o < 16; o <<= 1) ea += __shfl_xor(ea, o);
                float mn = fmaxf(m, ea);
                float sc = __expf(m - mn);
                float wa = __expf(ea - mn);
                s = s * sc + wa;
                r0 = fmaf(r0, sc, wa * va.x);
                r1 = fmaf(r1, sc, wa * va.y);
                r2 = fmaf(r2, sc, wa * va.z);
                r3 = fmaf(r3, sc, wa * va.w);
                m = mn;
            }

            if (l == 0) { mG[grp] = m; sG[grp] = s; }
            rG[grp][l * 4 + 0] = r0;
            rG[grp][l * 4 + 1] = r1;
            rG[grp][l * 4 + 2] = r2;
            rG[grp][l * 4 + 3] = r3;
            __syncthreads();

            if (t < 64) {
                float M = -INFINITY;
#pragma unroll
                for (int j2 = 0; j2 < 16; ++j2) M = fmaxf(M, mG[j2]);
                float out;
                if (M == -INFINITY) {
                    out = 0.0f;  // empty segment
                } else {
                    float ssum = 0.0f, racc = 0.0f;
#pragma unroll
                    for (int j2 = 0; j2 < 16; ++j2) {
                        float sc = __expf(mG[j2] - M);
                        ssum = fmaf(sG[j2], sc, ssum);
                        racc = fmaf(rG[j2][t], sc, racc);
                    }
                    out = racc / (ssum + 1e-16f);
                }
                uS[idx][64 + t] = out;
            }
            __syncthreads();
        }
    }

    // ---- head: wave w -> graph gbase+w; y = lin3(relu(lin2(q_star))) ----
    {
        const int d = lane;
        float a0 = l2b[d], a1 = 0.0f, a2 = 0.0f, a3 = 0.0f;
        for (int k = 0; k < 128; k += 4) {
            a0 = fmaf(l2T[(k + 0) * 64 + d], uS[w][k + 0], a0);
            a1 = fmaf(l2T[(k + 1) * 64 + d], uS[w][k + 1], a1);
            a2 = fmaf(l2T[(k + 2) * 64 + d], uS[w][k + 2], a2);
            a3 = fmaf(l2T[(k + 3) * 64 + d], uS[w][k + 3], a3);
        }
        float y = fmaxf((a0 + a1) + (a2 + a3), 0.0f);
        float p = l3w[d] * y;
#pragma unroll
        for (int o = 32; o > 0; o >>= 1) p += __shfl_xor(p, o);
        if (d == 0 && gbase + w < n_graphs) yout[gbase + w] = p + l3b[0];
    }
}

// ---------------------------------------------------------------------------
extern "C" void kernel_launch(void* const* d_in, const int* in_sizes, int n_in,
                              void* d_out, int out_size, void* d_ws, size_t ws_size,
                              hipStream_t stream)
{
    const float* x     = (const float*)d_in[0];
    const int*   batch = (const int*)d_in[1];
    const float* l0w   = (const float*)d_in[2];
    const float* l0b   = (const float*)d_in[3];
    const float* l1w   = (const float*)d_in[4];
    const float* l1b   = (const float*)d_in[5];
    const float* gwih  = (const float*)d_in[6];
    const float* gwhh  = (const float*)d_in[7];
    const float* gbih  = (const float*)d_in[8];
    const float* gbhh  = (const float*)d_in[9];
    const float* lwih  = (const float*)d_in[10];
    const float* lwhh  = (const float*)d_in[11];
    const float* lbih  = (const float*)d_in[12];
    const float* lbhh  = (const float*)d_in[13];
    const float* l2w   = (const float*)d_in[14];
    const float* l2b   = (const float*)d_in[15];
    const float* l3w   = (const float*)d_in[16];
    const float* l3b   = (const float*)d_in[17];

    const int n_nodes  = in_sizes[1];
    const int n_graphs = out_size;

    float* wsf = (float*)d_ws;
    float* outv = wsf;                                    // n_nodes*64 f32
    float* liT  = wsf + (size_t)n_nodes * 64;             // 32768 f32
    float* lhT  = liT + 32768;                            // 16384 f32
    float* l2T  = lhT + 16384;                            // 8192 f32
    unsigned short* whi = (unsigned short*)(l2T + 8192);  // 32768 u16
    unsigned short* wlo = whi + 32768;                    // 32768 u16
    int* startp = (int*)(wlo + 32768);                    // n_graphs+1

    prep_kernel<<<128, 256, 0, stream>>>(l0w, l1w, gwih, gwhh, lwih, lwhh, l2w, batch,
                                         whi, wlo, liT, lhT, l2T, startp,
                                         n_nodes, n_graphs);
    node_kernel<<<(n_nodes + MBLK - 1) / MBLK, 256, 0, stream>>>(
        x, whi, wlo, l0b, l1b, gbih, gbhh, outv, n_nodes);
    s2s_kernel<<<(n_graphs + 3) / 4, 256, 0, stream>>>(
        outv, startp, liT, lhT, lbih, lbhh, l2T, l2b, l3w, l3b,
        (float*)d_out, n_graphs);
}

// Round 12
// 716.372 us; speedup vs baseline: 1.0665x; 1.0665x over previous
//
#include <hip/hip_runtime.h>
#include <hip/hip_bf16.h>
#include <math.h>

#define TILES 4
#define MBLK 64

typedef __attribute__((ext_vector_type(8))) short bf8;
typedef __attribute__((ext_vector_type(4))) float f32x4;

#define MFMA(a, b, c) __builtin_amdgcn_mfma_f32_16x16x32_bf16(a, b, c, 0, 0, 0)

__device__ __forceinline__ float fast_rcp(float x) { return __builtin_amdgcn_rcpf(x); }
#if __has_builtin(__builtin_amdgcn_exp2f)
__device__ __forceinline__ float exp2b(float x) { return __builtin_amdgcn_exp2f(x); }
#else
__device__ __forceinline__ float exp2b(float x) { return exp2f(x); }
#endif
// log2e-prefolded sigmoid/tanh
__device__ __forceinline__ float sigm2(float xp) { return fast_rcp(1.0f + exp2b(-xp)); }
__device__ __forceinline__ float tanh2s(float up) {
    return fmaf(2.0f, fast_rcp(1.0f + exp2b(-up)), -1.0f);
}
// unscaled versions (s2s LSTM)
__device__ __forceinline__ float sigm(float x) { return fast_rcp(1.0f + __expf(-x)); }
__device__ __forceinline__ float tanh2(float x) { return fmaf(2.0f, fast_rcp(1.0f + __expf(-2.0f * x)), -1.0f); }

__device__ __forceinline__ unsigned short f2bf(float v) {
    union { __hip_bfloat16 b; unsigned short u; } cv;
    cv.b = __float2bfloat16(v);
    return cv.u;
}
__device__ __forceinline__ float bf2f(unsigned short u) {
    union { unsigned short u; __hip_bfloat16 b; } cv;
    cv.u = u;
    return __bfloat162float(cv.b);
}
// truncation split: hi = upper 16 bits (RTZ), lo = RNE(v - hi). err ~2^-17 rel.
__device__ __forceinline__ void split_tr(float v, unsigned short& hi, unsigned short& lo) {
    unsigned int uv = __builtin_bit_cast(unsigned int, v);
    hi = (unsigned short)(uv >> 16);
    float rem = v - __builtin_bit_cast(float, uv & 0xffff0000u);
    lo = f2bf(rem);
}

// ---------------------------------------------------------------------------
// prep (unchanged from round 11)
// ---------------------------------------------------------------------------
__global__ void prep_kernel(const float* __restrict__ l0w, const float* __restrict__ l1w,
                            const float* __restrict__ gwih, const float* __restrict__ gwhh,
                            const float* __restrict__ lwih, const float* __restrict__ lwhh,
                            const float* __restrict__ l2w,
                            const int* __restrict__ batch,
                            unsigned short* __restrict__ whi, unsigned short* __restrict__ wlo,
                            float* __restrict__ liT, float* __restrict__ lhT,
                            float* __restrict__ l2T,
                            int* __restrict__ startp,
                            int n_nodes, int n_graphs)
{
    int tid = blockIdx.x * 256 + threadIdx.x;
    if (tid < 32768) {
        int e = tid & 7, lane = (tid >> 3) & 63, ks = (tid >> 9) & 1, jt = tid >> 10;
        const float* W; int jl;
        if (jt < 4)       { W = l0w;  jl = jt; }
        else if (jt < 8)  { W = l1w;  jl = jt - 4; }
        else if (jt < 20) { W = gwih; jl = jt - 8; }
        else              { W = gwhh; jl = jt - 20; }
        int j = jl * 16 + (lane & 15);
        int k = ks * 32 + (lane >> 4) * 8 + e;
        float v = W[j * 64 + k];
        if (jt >= 8) v *= (j < 128) ? 1.44269504f : 2.88539008f;  // log2e / 2*log2e
        unsigned short hi = f2bf(v);
        whi[tid] = hi;
        wlo[tid] = f2bf(v - bf2f(hi));
    }
    if (tid < 32768) liT[tid] = lwih[(tid & 255) * 128 + (tid >> 8)];  // liT[k*256+j]
    if (tid < 16384) lhT[tid] = lwhh[(tid & 255) * 64 + (tid >> 8)];   // lhT[k*256+j]
    if (tid < 8192)  l2T[tid] = l2w[(tid & 63) * 128 + (tid >> 6)];    // l2T[k*64+d]
    if (tid <= n_graphs) {
        int lo = 0, hi = n_nodes;
        while (lo < hi) {
            int mid = (lo + hi) >> 1;
            if (batch[mid] < tid) lo = mid + 1; else hi = mid;
        }
        startp[tid] = lo;
    }
}

// ---------------------------------------------------------------------------
// node pipeline. Round-12 change: SOFTWARE PIPELINE across the tile loop —
// postprocess(t-1) VALU (nonlinearity/split/LDS store) issues under tile t's
// in-flight MFMA cluster (MFMA is fire-and-forget; same-wave independent VALU
// fills its shadow). Accumulators double-buffered (+16 regs, stays in the
// (128,256] bracket -> occupancy unchanged). H double-buffer + setprio kept.
// ---------------------------------------------------------------------------
__launch_bounds__(256, 2)
__global__ void node_kernel(const float* __restrict__ x,
                            const unsigned short* __restrict__ whi,
                            const unsigned short* __restrict__ wlo,
                            const float* __restrict__ l0b, const float* __restrict__ l1b,
                            const float* __restrict__ gbih, const float* __restrict__ gbhh,
                            float* __restrict__ outv, int n_nodes)
{
    __shared__ unsigned short MHI[TILES * 1024], MLO[TILES * 1024];
    __shared__ unsigned short HHI[2][TILES * 1024], HLO[2][TILES * 1024];
    const int tid = threadIdx.x;
    const int w = tid >> 6, lane = tid & 63, c = lane & 15, g = lane >> 4;
    const long node0 = (long)blockIdx.x * MBLK;
    const int j0 = w * 16 + g * 4;     // this thread's 4 channels (C rows)

    const float LOG2E = 1.44269504f;
    float bR[4], bZ[4], bNI[4], bNH[4], bL0[4], bL1[4];
#pragma unroll
    for (int p = 0; p < 4; ++p) {
        bR[p]  = (gbih[j0 + p] + gbhh[j0 + p]) * LOG2E;
        bZ[p]  = (gbih[64 + j0 + p] + gbhh[64 + j0 + p]) * LOG2E;
        bNI[p] = gbih[128 + j0 + p] * (2.0f * LOG2E);
        bNH[p] = gbhh[128 + j0 + p] * (2.0f * LOG2E);
        bL0[p] = l0b[j0 + p];
        bL1[p] = l1b[j0 + p];
    }

    // LDS write addr (u16): granule(node=c, kg=w*2+(g>>1)), elems (g&1)*4+p
    const int waddr = ((w >> 1) * 512) + (((w & 1) * 2 + (g >> 1)) * 128)
                    + (c * 8) + ((g & 1) * 4);

    const bf8* WH = (const bf8*)whi;
    const bf8* WL = (const bf8*)wlo;
#define LF(name, jt) \
    bf8 name##h0 = WH[((jt) * 2 + 0) * 64 + lane], name##h1 = WH[((jt) * 2 + 1) * 64 + lane], \
        name##l0 = WL[((jt) * 2 + 0) * 64 + lane], name##l1 = WL[((jt) * 2 + 1) * 64 + lane];
    LF(w0, w)
    LF(w1, 4 + w)
    LF(gir, 8 + w)  LF(giz, 12 + w)  LF(gin, 16 + w)
    LF(ghr, 20 + w) LF(ghz, 24 + w) LF(ghn, 28 + w)
#undef LF

    float hc[TILES][4];   // hc[t][p] = h[channel j0+p][node t*16+c]

    // ---- lin0: h = relu(W0 x + b0) -> H[0], pipelined ----
    {
        f32x4 accP;
#pragma unroll
        for (int t = 0; t < TILES; ++t) {
            long nd = node0 + t * 16 + c;
            if (nd >= n_nodes) nd = n_nodes - 1;
            const float* xp = x + nd * 64 + g * 8;
            float va[8], vb[8];
            {
                float4 u0 = *(const float4*)xp;
                float4 u1 = *(const float4*)(xp + 4);
                float4 u2 = *(const float4*)(xp + 32);
                float4 u3 = *(const float4*)(xp + 36);
                va[0] = u0.x; va[1] = u0.y; va[2] = u0.z; va[3] = u0.w;
                va[4] = u1.x; va[5] = u1.y; va[6] = u1.z; va[7] = u1.w;
                vb[0] = u2.x; vb[1] = u2.y; vb[2] = u2.z; vb[3] = u2.w;
                vb[4] = u3.x; vb[5] = u3.y; vb[6] = u3.z; vb[7] = u3.w;
            }
            bf8 xh0, xl0, xh1, xl1;
#pragma unroll
            for (int e = 0; e < 8; ++e) {
                unsigned short h0, l0, h1, l1;
                split_tr(va[e], h0, l0);
                split_tr(vb[e], h1, l1);
                xh0[e] = (short)h0; xl0[e] = (short)l0;
                xh1[e] = (short)h1; xl1[e] = (short)l1;
            }
            f32x4 acc = {bL0[0], bL0[1], bL0[2], bL0[3]};
            __builtin_amdgcn_s_setprio(1);
            acc = MFMA(w0h0, xh0, acc); acc = MFMA(w0h0, xl0, acc); acc = MFMA(w0l0, xh0, acc);
            acc = MFMA(w0h1, xh1, acc); acc = MFMA(w0h1, xl1, acc); acc = MFMA(w0l1, xh1, acc);
            __builtin_amdgcn_s_setprio(0);
            if (t > 0) {   // postprocess tile t-1 under tile t's MFMAs
                unsigned short sh[4], sl[4];
#pragma unroll
                for (int p = 0; p < 4; ++p) {
                    float hv = fmaxf(accP[p], 0.0f);
                    hc[t - 1][p] = hv;
                    split_tr(hv, sh[p], sl[p]);
                }
                *(short4*)&HHI[0][(t - 1) * 1024 + waddr] = make_short4((short)sh[0], (short)sh[1], (short)sh[2], (short)sh[3]);
                *(short4*)&HLO[0][(t - 1) * 1024 + waddr] = make_short4((short)sl[0], (short)sl[1], (short)sl[2], (short)sl[3]);
            }
            accP = acc;
        }
        {
            unsigned short sh[4], sl[4];
#pragma unroll
            for (int p = 0; p < 4; ++p) {
                float hv = fmaxf(accP[p], 0.0f);
                hc[TILES - 1][p] = hv;
                split_tr(hv, sh[p], sl[p]);
            }
            *(short4*)&HHI[0][(TILES - 1) * 1024 + waddr] = make_short4((short)sh[0], (short)sh[1], (short)sh[2], (short)sh[3]);
            *(short4*)&HLO[0][(TILES - 1) * 1024 + waddr] = make_short4((short)sl[0], (short)sl[1], (short)sl[2], (short)sl[3]);
        }
    }
    __syncthreads();

#pragma unroll
    for (int iter = 0; iter < 3; ++iter) {
        const int cur = iter & 1;
        const int nxt = cur ^ 1;

        // ---- lin1: m = relu(W1 h + b1), reads H[cur] -> M, pipelined ----
        {
            f32x4 accP;
#pragma unroll
            for (int t = 0; t < TILES; ++t) {
                const bf8* hh = (const bf8*)&HHI[cur][t * 1024];
                const bf8* hl = (const bf8*)&HLO[cur][t * 1024];
                bf8 ah0 = hh[lane], ah1 = hh[64 + lane];
                bf8 al0 = hl[lane], al1 = hl[64 + lane];
                f32x4 acc = {bL1[0], bL1[1], bL1[2], bL1[3]};
                __builtin_amdgcn_s_setprio(1);
                acc = MFMA(w1h0, ah0, acc); acc = MFMA(w1h0, al0, acc); acc = MFMA(w1l0, ah0, acc);
                acc = MFMA(w1h1, ah1, acc); acc = MFMA(w1h1, al1, acc); acc = MFMA(w1l1, ah1, acc);
                __builtin_amdgcn_s_setprio(0);
                if (t > 0) {   // postprocess tile t-1 under tile t's MFMAs
                    unsigned short sh[4], sl[4];
#pragma unroll
                    for (int p = 0; p < 4; ++p) {
                        float mv = fmaxf(accP[p], 0.0f);
                        split_tr(mv, sh[p], sl[p]);
                    }
                    *(short4*)&MHI[(t - 1) * 1024 + waddr] = make_short4((short)sh[0], (short)sh[1], (short)sh[2], (short)sh[3]);
                    *(short4*)&MLO[(t - 1) * 1024 + waddr] = make_short4((short)sl[0], (short)sl[1], (short)sl[2], (short)sl[3]);
                }
                accP = acc;
            }
            {
                unsigned short sh[4], sl[4];
#pragma unroll
                for (int p = 0; p < 4; ++p) {
                    float mv = fmaxf(accP[p], 0.0f);
                    split_tr(mv, sh[p], sl[p]);
                }
                *(short4*)&MHI[(TILES - 1) * 1024 + waddr] = make_short4((short)sh[0], (short)sh[1], (short)sh[2], (short)sh[3]);
                *(short4*)&MLO[(TILES - 1) * 1024 + waddr] = make_short4((short)sl[0], (short)sl[1], (short)sl[2], (short)sl[3]);
            }
        }
        __syncthreads();

        // ---- GRU gates: read M + H[cur], h -> H[nxt], pipelined ----
        {
            f32x4 pR, pZ, pNI, pNH;
#pragma unroll
            for (int t = 0; t < TILES; ++t) {
                const bf8* mh = (const bf8*)&MHI[t * 1024];
                const bf8* ml = (const bf8*)&MLO[t * 1024];
                const bf8* hh = (const bf8*)&HHI[cur][t * 1024];
                const bf8* hl = (const bf8*)&HLO[cur][t * 1024];
                bf8 amh0 = mh[lane], amh1 = mh[64 + lane];
                bf8 aml0 = ml[lane], aml1 = ml[64 + lane];
                bf8 ahh0 = hh[lane], ahh1 = hh[64 + lane];
                bf8 ahl0 = hl[lane], ahl1 = hl[64 + lane];

                f32x4 aR  = {bR[0], bR[1], bR[2], bR[3]};
                f32x4 aZ  = {bZ[0], bZ[1], bZ[2], bZ[3]};
                f32x4 aNI = {bNI[0], bNI[1], bNI[2], bNI[3]};
                f32x4 aNH = {bNH[0], bNH[1], bNH[2], bNH[3]};

                __builtin_amdgcn_s_setprio(1);
                aR = MFMA(girh0, amh0, aR); aR = MFMA(girh0, aml0, aR); aR = MFMA(girl0, amh0, aR);
                aR = MFMA(girh1, amh1, aR); aR = MFMA(girh1, aml1, aR); aR = MFMA(girl1, amh1, aR);
                aR = MFMA(ghrh0, ahh0, aR); aR = MFMA(ghrh0, ahl0, aR); aR = MFMA(ghrl0, ahh0, aR);
                aR = MFMA(ghrh1, ahh1, aR); aR = MFMA(ghrh1, ahl1, aR); aR = MFMA(ghrl1, ahh1, aR);

                aZ = MFMA(gizh0, amh0, aZ); aZ = MFMA(gizh0, aml0, aZ); aZ = MFMA(gizl0, amh0, aZ);
                aZ = MFMA(gizh1, amh1, aZ); aZ = MFMA(gizh1, aml1, aZ); aZ = MFMA(gizl1, amh1, aZ);
                aZ = MFMA(ghzh0, ahh0, aZ); aZ = MFMA(ghzh0, ahl0, aZ); aZ = MFMA(ghzl0, ahh0, aZ);
                aZ = MFMA(ghzh1, ahh1, aZ); aZ = MFMA(ghzh1, ahl1, aZ); aZ = MFMA(ghzl1, ahh1, aZ);

                aNI = MFMA(ginh0, amh0, aNI); aNI = MFMA(ginh0, aml0, aNI); aNI = MFMA(ginl0, amh0, aNI);
                aNI = MFMA(ginh1, amh1, aNI); aNI = MFMA(ginh1, aml1, aNI); aNI = MFMA(ginl1, amh1, aNI);

                aNH = MFMA(ghnh0, ahh0, aNH); aNH = MFMA(ghnh0, ahl0, aNH); aNH = MFMA(ghnl0, ahh0, aNH);
                aNH = MFMA(ghnh1, ahh1, aNH); aNH = MFMA(ghnh1, ahl1, aNH); aNH = MFMA(ghnl1, ahh1, aNH);
                __builtin_amdgcn_s_setprio(0);

                if (t > 0) {   // postprocess tile t-1 under tile t's MFMAs
                    unsigned short sh[4], sl[4];
#pragma unroll
                    for (int p = 0; p < 4; ++p) {
                        float rg = sigm2(pR[p]);
                        float zg = sigm2(pZ[p]);
                        float ng = tanh2s(fmaf(rg, pNH[p], pNI[p]));
                        float hv = fmaf(zg, hc[t - 1][p] - ng, ng);
                        hc[t - 1][p] = hv;
                        split_tr(hv, sh[p], sl[p]);
                    }
                    if (iter < 2) {
                        *(short4*)&HHI[nxt][(t - 1) * 1024 + waddr] = make_short4((short)sh[0], (short)sh[1], (short)sh[2], (short)sh[3]);
                        *(short4*)&HLO[nxt][(t - 1) * 1024 + waddr] = make_short4((short)sl[0], (short)sl[1], (short)sl[2], (short)sl[3]);
                    }
                }
                pR = aR; pZ = aZ; pNI = aNI; pNH = aNH;
            }
            {
                unsigned short sh[4], sl[4];
#pragma unroll
                for (int p = 0; p < 4; ++p) {
                    float rg = sigm2(pR[p]);
                    float zg = sigm2(pZ[p]);
                    float ng = tanh2s(fmaf(rg, pNH[p], pNI[p]));
                    float hv = fmaf(zg, hc[TILES - 1][p] - ng, ng);
                    hc[TILES - 1][p] = hv;
                    split_tr(hv, sh[p], sl[p]);
                }
                if (iter < 2) {
                    *(short4*)&HHI[nxt][(TILES - 1) * 1024 + waddr] = make_short4((short)sh[0], (short)sh[1], (short)sh[2], (short)sh[3]);
                    *(short4*)&HLO[nxt][(TILES - 1) * 1024 + waddr] = make_short4((short)sl[0], (short)sl[1], (short)sl[2], (short)sl[3]);
                }
            }
        }
        if (iter < 2) __syncthreads();
    }

    // ---- store out: thread owns channels j0..j0+3 of node t*16+c ----
#pragma unroll
    for (int t = 0; t < TILES; ++t) {
        long nd = node0 + t * 16 + c;
        if (nd < n_nodes) {
            float4 o;
            o.x = hc[t][0]; o.y = hc[t][1]; o.z = hc[t][2]; o.w = hc[t][3];
            *(float4*)(outv + nd * 64 + j0) = o;
        }
    }
}

// ---------------------------------------------------------------------------
// FUSED Set2Set (3 steps) + head. Round-12 change: PLAIN loads (no nt hint) —
// outv (256MB) ~fits the 256MiB L3 and is re-read 3x; nt forfeited that reuse.
// ---------------------------------------------------------------------------
__global__ void s2s_kernel(const float* __restrict__ outv,
                           const int* __restrict__ startp,
                           const float* __restrict__ liT, const float* __restrict__ lhT,
                           const float* __restrict__ lbih, const float* __restrict__ lbhh,
                           const float* __restrict__ l2T, const float* __restrict__ l2b,
                           const float* __restrict__ l3w, const float* __restrict__ l3b,
                           float* __restrict__ yout, int n_graphs)
{
    __shared__ float uS[4][192];   // per graph: [0:64) q, [64:128) r, [128:192) hl
    __shared__ float clS[4][64];
    __shared__ float mG[16], sG[16];
    __shared__ float rG[16][64];

    const int t = threadIdx.x;
    const int w = t >> 6, lane = t & 63;
    const int gbase = blockIdx.x * 4;
    const int grp = t >> 4, l = t & 15;

    uS[w][lane] = 0.0f; uS[w][64 + lane] = 0.0f; uS[w][128 + lane] = 0.0f;
    clS[w][lane] = 0.0f;
    __syncthreads();

    for (int step = 0; step < 3; ++step) {
        // ---- LSTM: wave w -> graph gbase+w, lane = channel d ----
        {
            const int d = lane;
            float aI = lbih[d]       + lbhh[d];
            float aF = lbih[64 + d]  + lbhh[64 + d];
            float aG = lbih[128 + d] + lbhh[128 + d];
            float aO = lbih[192 + d] + lbhh[192 + d];
            for (int k = 0; k < 128; ++k) {
                float uv = uS[w][k];
                const float* wr = liT + k * 256;
                aI = fmaf(wr[d], uv, aI);
                aF = fmaf(wr[64 + d], uv, aF);
                aG = fmaf(wr[128 + d], uv, aG);
                aO = fmaf(wr[192 + d], uv, aO);
            }
            for (int k = 0; k < 64; ++k) {
                float hv = uS[w][128 + k];
                const float* wr = lhT + k * 256;
                aI = fmaf(wr[d], hv, aI);
                aF = fmaf(wr[64 + d], hv, aF);
                aG = fmaf(wr[128 + d], hv, aG);
                aO = fmaf(wr[192 + d], hv, aO);
            }
            float c = sigm(aF) * clS[w][d] + sigm(aI) * tanh2(aG);
            clS[w][d] = c;
            float h = sigm(aO) * tanh2(c);
            uS[w][d] = h;        // q
            uS[w][128 + d] = h;  // hl
        }
        __syncthreads();

        // ---- attention: 4 graphs serially, all 256 threads each ----
        for (int idx = 0; idx < 4; ++idx) {
            const int g = gbase + idx;
            int s0 = 0, cnt = 0;
            if (g < n_graphs) { s0 = startp[g]; cnt = startp[g + 1] - s0; }

            const float q0 = uS[idx][l * 4 + 0], q1 = uS[idx][l * 4 + 1];
            const float q2 = uS[idx][l * 4 + 2], q3 = uS[idx][l * 4 + 3];

            float m = -INFINITY, s = 0.0f;
            float r0 = 0.0f, r1 = 0.0f, r2 = 0.0f, r3 = 0.0f;

            int n = grp;
            for (; n + 16 < cnt; n += 32) {
                f32x4 va = *(const f32x4*)(outv + (size_t)(s0 + n) * 64 + l * 4);
                f32x4 vb = *(const f32x4*)(outv + (size_t)(s0 + n + 16) * 64 + l * 4);
                float ea = fmaf(va.x, q0, fmaf(va.y, q1, fmaf(va.z, q2, va.w * q3)));
                float eb = fmaf(vb.x, q0, fmaf(vb.y, q1, fmaf(vb.z, q2, vb.w * q3)));
#pragma unroll
                for (int o = 1; o < 16; o <<= 1) {
                    ea += __shfl_xor(ea, o);
                    eb += __shfl_xor(eb, o);
                }
                float mn = fmaxf(m, fmaxf(ea, eb));
                float sc = __expf(m - mn);
                float wa = __expf(ea - mn);
                float wb = __expf(eb - mn);
                s = s * sc + wa + wb;
                r0 = fmaf(r0, sc, fmaf(wa, va.x, wb * vb.x));
                r1 = fmaf(r1, sc, fmaf(wa, va.y, wb * vb.y));
                r2 = fmaf(r2, sc, fmaf(wa, va.z, wb * vb.z));
                r3 = fmaf(r3, sc, fmaf(wa, va.w, wb * vb.w));
                m = mn;
            }
            if (n < cnt) {
                f32x4 va = *(const f32x4*)(outv + (size_t)(s0 + n) * 64 + l * 4);
                float ea = fmaf(va.x, q0, fmaf(va.y, q1, fmaf(va.z, q2, va.w * q3)));
#pragma unroll
                for (int o = 1; o < 16; o <<= 1) ea += __shfl_xor(ea, o);
                float mn = fmaxf(m, ea);
                float sc = __expf(m - mn);
                float wa = __expf(ea - mn);
                s = s * sc + wa;
                r0 = fmaf(r0, sc, wa * va.x);
                r1 = fmaf(r1, sc, wa * va.y);
                r2 = fmaf(r2, sc, wa * va.z);
                r3 = fmaf(r3, sc, wa * va.w);
                m = mn;
            }

            if (l == 0) { mG[grp] = m; sG[grp] = s; }
            rG[grp][l * 4 + 0] = r0;
            rG[grp][l * 4 + 1] = r1;
            rG[grp][l * 4 + 2] = r2;
            rG[grp][l * 4 + 3] = r3;
            __syncthreads();

            if (t < 64) {
                float M = -INFINITY;
#pragma unroll
                for (int j2 = 0; j2 < 16; ++j2) M = fmaxf(M, mG[j2]);
                float out;
                if (M == -INFINITY) {
                    out = 0.0f;  // empty segment
                } else {
                    float ssum = 0.0f, racc = 0.0f;
#pragma unroll
                    for (int j2 = 0; j2 < 16; ++j2) {
                        float sc = __expf(mG[j2] - M);
                        ssum = fmaf(sG[j2], sc, ssum);
                        racc = fmaf(rG[j2][t], sc, racc);
                    }
                    out = racc / (ssum + 1e-16f);
                }
                uS[idx][64 + t] = out;
            }
            __syncthreads();
        }
    }

    // ---- head: wave w -> graph gbase+w; y = lin3(relu(lin2(q_star))) ----
    {
        const int d = lane;
        float a0 = l2b[d], a1 = 0.0f, a2 = 0.0f, a3 = 0.0f;
        for (int k = 0; k < 128; k += 4) {
            a0 = fmaf(l2T[(k + 0) * 64 + d], uS[w][k + 0], a0);
            a1 = fmaf(l2T[(k + 1) * 64 + d], uS[w][k + 1], a1);
            a2 = fmaf(l2T[(k + 2) * 64 + d], uS[w][k + 2], a2);
            a3 = fmaf(l2T[(k + 3) * 64 + d], uS[w][k + 3], a3);
        }
        float y = fmaxf((a0 + a1) + (a2 + a3), 0.0f);
        float p = l3w[d] * y;
#pragma unroll
        for (int o = 32; o > 0; o >>= 1) p += __shfl_xor(p, o);
        if (d == 0 && gbase + w < n_graphs) yout[gbase + w] = p + l3b[0];
    }
}

// ---------------------------------------------------------------------------
extern "C" void kernel_launch(void* const* d_in, const int* in_sizes, int n_in,
                              void* d_out, int out_size, void* d_ws, size_t ws_size,
                              hipStream_t stream)
{
    const float* x     = (const float*)d_in[0];
    const int*   batch = (const int*)d_in[1];
    const float* l0w   = (const float*)d_in[2];
    const float* l0b   = (const float*)d_in[3];
    const float* l1w   = (const float*)d_in[4];
    const float* l1b   = (const float*)d_in[5];
    const float* gwih  = (const float*)d_in[6];
    const float* gwhh  = (const float*)d_in[7];
    const float* gbih  = (const float*)d_in[8];
    const float* gbhh  = (const float*)d_in[9];
    const float* lwih  = (const float*)d_in[10];
    const float* lwhh  = (const float*)d_in[11];
    const float* lbih  = (const float*)d_in[12];
    const float* lbhh  = (const float*)d_in[13];
    const float* l2w   = (const float*)d_in[14];
    const float* l2b   = (const float*)d_in[15];
    const float* l3w   = (const float*)d_in[16];
    const float* l3b   = (const float*)d_in[17];

    const int n_nodes  = in_sizes[1];
    const int n_graphs = out_size;

    float* wsf = (float*)d_ws;
    float* outv = wsf;                                    // n_nodes*64 f32
    float* liT  = wsf + (size_t)n_nodes * 64;             // 32768 f32
    float* lhT  = liT + 32768;                            // 16384 f32
    float* l2T  = lhT + 16384;                            // 8192 f32
    unsigned short* whi = (unsigned short*)(l2T + 8192);  // 32768 u16
    unsigned short* wlo = whi + 32768;                    // 32768 u16
    int* startp = (int*)(wlo + 32768);                    // n_graphs+1

    prep_kernel<<<128, 256, 0, stream>>>(l0w, l1w, gwih, gwhh, lwih, lwhh, l2w, batch,
                                         whi, wlo, liT, lhT, l2T, startp,
                                         n_nodes, n_graphs);
    node_kernel<<<(n_nodes + MBLK - 1) / MBLK, 256, 0, stream>>>(
        x, whi, wlo, l0b, l1b, gbih, gbhh, outv, n_nodes);
    s2s_kernel<<<(n_graphs + 3) / 4, 256, 0, stream>>>(
        outv, startp, liT, lhT, lbih, lbhh, l2T, l2b, l3w, l3b,
        (float*)d_out, n_graphs);
}